// Round 5
// baseline (290.859 us; speedup 1.0000x reference)
//
#include <hip/hip_runtime.h>

#define S_DIM 2048
#define K_DIM 4096
#define O_DIM 4096
#define NNON  3968   // H - KEEPER
#define NB    31     // low-precision blocks

#define XBLK 8192    // scale_x segment blocks:  S*K/4/256
#define WBLK 16384   // scale_w segment blocks:  O*K/4/256

typedef __bf16 bf16x8 __attribute__((ext_vector_type(8)));
typedef float  f32x4  __attribute__((ext_vector_type(4)));

__device__ __forceinline__ unsigned short f2bf(float f) {
    union { float f; unsigned u; } v; v.f = f;
    unsigned r = v.u + 0x7FFFu + ((v.u >> 16) & 1u);   // round-to-nearest-even
    return (unsigned short)(r >> 16);
}

// One fused prepass launch, two block-uniform segments:
//   [0, XBLK)           A'[s,k] = bf16(x * sc_lo/hi)
//   [XBLK, XBLK+WBLK)   B'[o,k] = bf16(w * scales/keep)
__global__ __launch_bounds__(256) void prepass(const float* __restrict__ x,
                                               const float* __restrict__ sc_lo,
                                               const float* __restrict__ sc_hi,
                                               const float* __restrict__ w,
                                               const float* __restrict__ scales,
                                               const float* __restrict__ keep,
                                               unsigned short* __restrict__ A,
                                               unsigned short* __restrict__ B)
{
    const int b = blockIdx.x;
    if (b < XBLK) {
        int idx = b * 256 + threadIdx.x;           // over S*K/4, K/4 = 1024
        int s = idx >> 10;
        int k = (idx & 1023) << 2;                 // 4 elems never straddle a 128-block
        float4 v = ((const float4*)x)[idx];
        float sc = (k < NNON) ? sc_lo[s * NB + (k >> 7)] : sc_hi[s];
        ushort4 o;
        o.x = f2bf(v.x * sc); o.y = f2bf(v.y * sc);
        o.z = f2bf(v.z * sc); o.w = f2bf(v.w * sc);
        ((ushort4*)A)[idx] = o;
    } else {
        int idx = (b - XBLK) * 256 + threadIdx.x;  // over O*K/4
        int o = idx >> 10;
        int k = (idx & 1023) << 2;
        float4 v = ((const float4*)w)[idx];
        float sc = (k < NNON) ? scales[(size_t)o * NNON + ((k >> 7) << 7)] : keep[o];
        ushort4 r;
        r.x = f2bf(v.x * sc); r.y = f2bf(v.y * sc);
        r.z = f2bf(v.z * sc); r.w = f2bf(v.w * sc);
        ((ushort4*)B)[idx] = r;
    }
}

// R11: exact m201 geometry (the ONLY structure that has ever beaten ~930 TF
// in plain HIP on this chip) + split-K=2 to fill the grid at M=2048.
//   BM=BN=256, BK=64, 512 thr = 8 waves (2M x 4N), wave tile 128x64,
//   LDS 128 KB (2dbuf x (A 32KB + B 32KB)). Grid 256 = 8bm x 16bn x 2ksl.
//   Per iter: 2 K-tiles (E=2i buf0, O=2i+1 buf1), 8 phases x
//   {ds_read; stage; barrier; lgkmcnt(0); setprio(1); 16 MFMA; setprio(0);
//    [vmcnt]; barrier}.
//   Reads (per wave): p1 E.Alo(8)+E.B0(4); p2 E.B1(4); p3 E.Ahi(8); p4 -;
//                     p5 O.Alo+O.B0(12);   p6 O.B1(4); p7 O.Ahi(8); p8 -.
//   Slab consumption (128-row staging halves; wave tiles straddle BOTH
//   A-slabs): A-slabs free after p3/p7; B-slabs after p2/p6.
//   Stage ledger (1-2 halves/phase, slot-free at issue, race-audited):
//     p1: A1(O)       [A1 buf1 read @p7 prev iter; completes tile O]
//     p3: B0(E+2)     [buf0 B0 free after p2]
//     p4: A0(E+2)     [buf0 A free after p3]
//     p5: A1(E+2) + B1(E+2)
//     p7: B0(O+2)     [buf1 B free after p6]
//     p8: A0(O+2) + B1(O+2)
//   Waits: p4-end vmcnt(4) keeps {p3,p4} -> retires through p1 => ALL of O
//   resident before p5 reads. p8-end vmcnt(6) keeps {p7,p8} -> retires
//   through p5 => ALL of E+2 resident before next-iter p1 reads.
//   Prologue mirrors steady state: stage E0 (4 halves) + O1.{B0,B1,A0};
//   vmcnt(6) retires E0. Tail: it==NIT-1 skips E+2/O+2 stages, p4 uses
//   vmcnt(0) (tile O=31 completed by p1's stage).
//   Split-K epilogue: unsafeAtomicAdd into memset-zeroed C; XCD swizzle
//   puts both K-slices of a tile on the SAME XCD (atomic lines stay in
//   one L2; A-panels 16-way reused within the XCD).
#define BM 256
#define BN 256
#define BK 64
#define KSLICE 2048
#define NTK (KSLICE / BK)   // 32 K-tiles per slice
#define NIT (NTK / 2)       // 16 iterations of 2 K-tiles

#define GPTR(p) ((__attribute__((address_space(1))) unsigned int*)(p))
#define LPTR(p) ((__attribute__((address_space(3))) unsigned int*)(p))

__device__ __forceinline__ void vm_wait6() { asm volatile("s_waitcnt vmcnt(6)" ::: "memory"); }
__device__ __forceinline__ void vm_wait4() { asm volatile("s_waitcnt vmcnt(4)" ::: "memory"); }
__device__ __forceinline__ void vm_wait0() { asm volatile("s_waitcnt vmcnt(0)" ::: "memory"); }
__device__ __forceinline__ void lgkm0()    { asm volatile("s_waitcnt lgkmcnt(0)" ::: "memory"); }
__device__ __forceinline__ void wg_barrier() {
    asm volatile("" ::: "memory");
    __builtin_amdgcn_s_barrier();
    asm volatile("" ::: "memory");
}

__global__ __launch_bounds__(512, 2) void gemm_bt(const unsigned short* __restrict__ A,
                                                  const unsigned short* __restrict__ B,
                                                  float* __restrict__ C)
{
    __shared__ __align__(16) unsigned short As[2][BM * BK];   // 2 x 32 KB
    __shared__ __align__(16) unsigned short Bs[2][BN * BK];   // 2 x 32 KB

    const int tid  = threadIdx.x;
    const int wave = tid >> 6;        // 0..7
    const int lane = tid & 63;
    const int quad = lane >> 4;
    const int l16  = lane & 15;

    // XCD swizzle: XCD x <- sw in [32x, 32x+32) = 1 bm-row x 16 bn x 2 ksl.
    const int wg  = blockIdx.x;                  // 0..255
    const int sw  = (wg & 7) * 32 + (wg >> 3);
    const int bm  = (sw >> 5) * BM;              // 8 M-tiles
    const int bn  = ((sw >> 1) & 15) * BN;       // 16 N-tiles
    const int ksl = sw & 1;
    const int kbase = ksl * KSLICE;

    const int wm = (wave >> 2) * 128;            // wave rows (2 M-positions)
    const int wn = (wave & 3) * 64;              // wave cols (4 N-positions)

    // staging lanes: row r8 = lane>>3, dest 16B chunk q8 = lane&7;
    // source column chunk pre-swizzled: q8 ^ (row&7) = q8 ^ r8.
    const int r8 = lane >> 3;
    const int q8 = lane & 7;
    const unsigned short* Ag = A + (size_t)(bm + wave * 8 + r8) * K_DIM + kbase + ((q8 ^ r8) << 3);
    const unsigned short* Bg = B + (size_t)(bn + wave * 8 + r8) * K_DIM + kbase + ((q8 ^ r8) << 3);

    f32x4 acc[8][4];
    #pragma unroll
    for (int ii = 0; ii < 8; ++ii)
        #pragma unroll
        for (int j = 0; j < 4; ++j)
            acc[ii][j] = (f32x4){0.f, 0.f, 0.f, 0.f};

    // stage one 128-row half-slab (h) of K-tile t: 2 DMA/thread, 8 waves
    // cover 64 rows/DMA round.
    auto stageA = [&](int t, int h) {
        unsigned short* dst = &As[t & 1][(h * 128 + wave * 8) * BK];
        const unsigned short* src = Ag + (size_t)(h * 128) * K_DIM + t * BK;
        #pragma unroll
        for (int s = 0; s < 2; ++s)
            __builtin_amdgcn_global_load_lds(GPTR(src + (size_t)(s * 64) * K_DIM),
                                             LPTR(dst + s * 64 * BK), 16, 0, 0);
    };
    auto stageB = [&](int t, int h) {
        unsigned short* dst = &Bs[t & 1][(h * 128 + wave * 8) * BK];
        const unsigned short* src = Bg + (size_t)(h * 128) * K_DIM + t * BK;
        #pragma unroll
        for (int s = 0; s < 2; ++s)
            __builtin_amdgcn_global_load_lds(GPTR(src + (size_t)(s * 64) * K_DIM),
                                             LPTR(dst + s * 64 * BK), 16, 0, 0);
    };

    // prologue: E0 fully (4 halves) + O1.{B0,B1,A0} (3 halves) = 14 loads.
    // vmcnt(6) keeps the newest 3 halves (= steady-state set), retires E0.
    stageB(0, 0); stageA(0, 0); stageA(0, 1); stageB(0, 1);
    stageB(1, 0); stageB(1, 1); stageA(1, 0);
    vm_wait6();
    wg_barrier();

    // reader un-swizzle: chunk c at row r lives in slot c ^ (r&7); all
    // frag-read rows have (row&7) == (l16&7); chunk = ks*4 + quad.
    const int co0 = ((quad)     ^ (l16 & 7)) << 3;   // kslice 0
    const int co1 = ((4 + quad) ^ (l16 & 7)) << 3;   // kslice 1

    #pragma unroll 1
    for (int it = 0; it < NIT; ++it) {
        const bool more = (it < NIT - 1);
        const int O  = 2 * it + 1;
        const int En = 2 * it + 2;
        const int On = 2 * it + 3;

        bf16x8 alo[2][4], ahi[2][4], b0[2][2], b1[2][2];

        // ---- p1: read E.Alo + E.B0; stage A1(O); mfma acc[0..3][0..1]
        #pragma unroll
        for (int ii = 0; ii < 4; ++ii) {
            alo[0][ii] = *(const bf16x8*)&As[0][(wm + ii * 16 + l16) * BK + co0];
            alo[1][ii] = *(const bf16x8*)&As[0][(wm + ii * 16 + l16) * BK + co1];
        }
        #pragma unroll
        for (int j = 0; j < 2; ++j) {
            b0[0][j] = *(const bf16x8*)&Bs[0][(wn + j * 16 + l16) * BK + co0];
            b0[1][j] = *(const bf16x8*)&Bs[0][(wn + j * 16 + l16) * BK + co1];
        }
        stageA(O, 1);
        wg_barrier(); lgkm0();
        __builtin_amdgcn_s_setprio(1);
        #pragma unroll
        for (int ks = 0; ks < 2; ++ks)
            #pragma unroll
            for (int ii = 0; ii < 4; ++ii)
                #pragma unroll
                for (int j = 0; j < 2; ++j)
                    acc[ii][j] = __builtin_amdgcn_mfma_f32_16x16x32_bf16(alo[ks][ii], b0[ks][j],
                                                                         acc[ii][j], 0, 0, 0);
        __builtin_amdgcn_s_setprio(0);
        wg_barrier();

        // ---- p2: read E.B1; mfma acc[0..3][2..3]
        #pragma unroll
        for (int j = 0; j < 2; ++j) {
            b1[0][j] = *(const bf16x8*)&Bs[0][(wn + 32 + j * 16 + l16) * BK + co0];
            b1[1][j] = *(const bf16x8*)&Bs[0][(wn + 32 + j * 16 + l16) * BK + co1];
        }
        wg_barrier(); lgkm0();
        __builtin_amdgcn_s_setprio(1);
        #pragma unroll
        for (int ks = 0; ks < 2; ++ks)
            #pragma unroll
            for (int ii = 0; ii < 4; ++ii)
                #pragma unroll
                for (int j = 0; j < 2; ++j)
                    acc[ii][j + 2] = __builtin_amdgcn_mfma_f32_16x16x32_bf16(alo[ks][ii], b1[ks][j],
                                                                             acc[ii][j + 2], 0, 0, 0);
        __builtin_amdgcn_s_setprio(0);
        wg_barrier();

        // ---- p3: read E.Ahi; stage B0(E+2); mfma acc[4..7][2..3]
        #pragma unroll
        for (int ii = 0; ii < 4; ++ii) {
            ahi[0][ii] = *(const bf16x8*)&As[0][(wm + 64 + ii * 16 + l16) * BK + co0];
            ahi[1][ii] = *(const bf16x8*)&As[0][(wm + 64 + ii * 16 + l16) * BK + co1];
        }
        if (more) stageB(En, 0);
        wg_barrier(); lgkm0();
        __builtin_amdgcn_s_setprio(1);
        #pragma unroll
        for (int ks = 0; ks < 2; ++ks)
            #pragma unroll
            for (int ii = 0; ii < 4; ++ii)
                #pragma unroll
                for (int j = 0; j < 2; ++j)
                    acc[ii + 4][j + 2] = __builtin_amdgcn_mfma_f32_16x16x32_bf16(ahi[ks][ii], b1[ks][j],
                                                                                 acc[ii + 4][j + 2], 0, 0, 0);
        __builtin_amdgcn_s_setprio(0);
        wg_barrier();

        // ---- p4: stage A0(E+2); mfma acc[4..7][0..1]; vmcnt(4) -> O resident
        if (more) stageA(En, 0);
        wg_barrier();
        __builtin_amdgcn_s_setprio(1);
        #pragma unroll
        for (int ks = 0; ks < 2; ++ks)
            #pragma unroll
            for (int ii = 0; ii < 4; ++ii)
                #pragma unroll
                for (int j = 0; j < 2; ++j)
                    acc[ii + 4][j] = __builtin_amdgcn_mfma_f32_16x16x32_bf16(ahi[ks][ii], b0[ks][j],
                                                                             acc[ii + 4][j], 0, 0, 0);
        __builtin_amdgcn_s_setprio(0);
        if (more) vm_wait4(); else vm_wait0();
        wg_barrier();

        // ---- p5: read O.Alo + O.B0; stage A1(E+2) + B1(E+2); mfma [0..3][0..1]
        #pragma unroll
        for (int ii = 0; ii < 4; ++ii) {
            alo[0][ii] = *(const bf16x8*)&As[1][(wm + ii * 16 + l16) * BK + co0];
            alo[1][ii] = *(const bf16x8*)&As[1][(wm + ii * 16 + l16) * BK + co1];
        }
        #pragma unroll
        for (int j = 0; j < 2; ++j) {
            b0[0][j] = *(const bf16x8*)&Bs[1][(wn + j * 16 + l16) * BK + co0];
            b0[1][j] = *(const bf16x8*)&Bs[1][(wn + j * 16 + l16) * BK + co1];
        }
        if (more) { stageA(En, 1); stageB(En, 1); }
        wg_barrier(); lgkm0();
        __builtin_amdgcn_s_setprio(1);
        #pragma unroll
        for (int ks = 0; ks < 2; ++ks)
            #pragma unroll
            for (int ii = 0; ii < 4; ++ii)
                #pragma unroll
                for (int j = 0; j < 2; ++j)
                    acc[ii][j] = __builtin_amdgcn_mfma_f32_16x16x32_bf16(alo[ks][ii], b0[ks][j],
                                                                         acc[ii][j], 0, 0, 0);
        __builtin_amdgcn_s_setprio(0);
        wg_barrier();

        // ---- p6: read O.B1; mfma acc[0..3][2..3]
        #pragma unroll
        for (int j = 0; j < 2; ++j) {
            b1[0][j] = *(const bf16x8*)&Bs[1][(wn + 32 + j * 16 + l16) * BK + co0];
            b1[1][j] = *(const bf16x8*)&Bs[1][(wn + 32 + j * 16 + l16) * BK + co1];
        }
        wg_barrier(); lgkm0();
        __builtin_amdgcn_s_setprio(1);
        #pragma unroll
        for (int ks = 0; ks < 2; ++ks)
            #pragma unroll
            for (int ii = 0; ii < 4; ++ii)
                #pragma unroll
                for (int j = 0; j < 2; ++j)
                    acc[ii][j + 2] = __builtin_amdgcn_mfma_f32_16x16x32_bf16(alo[ks][ii], b1[ks][j],
                                                                             acc[ii][j + 2], 0, 0, 0);
        __builtin_amdgcn_s_setprio(0);
        wg_barrier();

        // ---- p7: read O.Ahi; stage B0(O+2); mfma acc[4..7][2..3]
        #pragma unroll
        for (int ii = 0; ii < 4; ++ii) {
            ahi[0][ii] = *(const bf16x8*)&As[1][(wm + 64 + ii * 16 + l16) * BK + co0];
            ahi[1][ii] = *(const bf16x8*)&As[1][(wm + 64 + ii * 16 + l16) * BK + co1];
        }
        if (more) stageB(On, 0);
        wg_barrier(); lgkm0();
        __builtin_amdgcn_s_setprio(1);
        #pragma unroll
        for (int ks = 0; ks < 2; ++ks)
            #pragma unroll
            for (int ii = 0; ii < 4; ++ii)
                #pragma unroll
                for (int j = 0; j < 2; ++j)
                    acc[ii + 4][j + 2] = __builtin_amdgcn_mfma_f32_16x16x32_bf16(ahi[ks][ii], b1[ks][j],
                                                                                 acc[ii + 4][j + 2], 0, 0, 0);
        __builtin_amdgcn_s_setprio(0);
        wg_barrier();

        // ---- p8: stage A0(O+2)+B1(O+2); mfma acc[4..7][0..1]; vmcnt(6)
        if (more) { stageA(On, 0); stageB(On, 1); }
        wg_barrier();
        __builtin_amdgcn_s_setprio(1);
        #pragma unroll
        for (int ks = 0; ks < 2; ++ks)
            #pragma unroll
            for (int ii = 0; ii < 4; ++ii)
                #pragma unroll
                for (int j = 0; j < 2; ++j)
                    acc[ii + 4][j] = __builtin_amdgcn_mfma_f32_16x16x32_bf16(ahi[ks][ii], b0[ks][j],
                                                                             acc[ii + 4][j], 0, 0, 0);
        __builtin_amdgcn_s_setprio(0);
        if (more) vm_wait6();   // retires through p5 -> E+2 resident next p1
        wg_barrier();
    }

    // epilogue: C/D layout (m89-verified): col = lane&15, row = quad*4 + reg.
    // Two K-slices accumulate into memset-zeroed C via HW f32 atomics
    // (fire-and-forget global_atomic_add; both contenders on the same XCD).
    #pragma unroll
    for (int ii = 0; ii < 8; ++ii)
        #pragma unroll
        for (int j = 0; j < 4; ++j) {
            const int col = bn + wn + j * 16 + l16;
            #pragma unroll
            for (int r = 0; r < 4; ++r) {
                const int row = bm + wm + ii * 16 + quad * 4 + r;
                unsafeAtomicAdd(&C[(size_t)row * O_DIM + col], acc[ii][j][r]);
            }
        }
}

extern "C" void kernel_launch(void* const* d_in, const int* in_sizes, int n_in,
                              void* d_out, int out_size, void* d_ws, size_t ws_size,
                              hipStream_t stream) {
    const float* x      = (const float*)d_in[0];
    const float* weight = (const float*)d_in[1];  // [O, K]
    const float* scales = (const float*)d_in[2];  // [O, NNON]
    const float* keep   = (const float*)d_in[3];  // [O, 1]
    const float* sc_lo  = (const float*)d_in[4];  // [S, NB]
    const float* sc_hi  = (const float*)d_in[5];  // [S, 1]
    // d_in[6], d_in[7] (inp_base_lo/hi) unused by reference

    // workspace: A' 16 MB @ 0, B' 32 MB @ 16 MB (needs 48 MB of d_ws)
    unsigned short* A = (unsigned short*)d_ws;
    unsigned short* B = A + (size_t)S_DIM * K_DIM;

    hipMemsetAsync(d_out, 0, (size_t)S_DIM * O_DIM * sizeof(float), stream);
    prepass<<<XBLK + WBLK, 256, 0, stream>>>(x, sc_lo, sc_hi, weight, scales, keep, A, B);

    dim3 grid(256);   // 8 bm x 16 bn x 2 ksl, XCD-swizzled in-kernel
    gemm_bt<<<grid, 512, 0, stream>>>(A, B, (float*)d_out);
}